// Round 3
// baseline (259.225 us; speedup 1.0000x reference)
//
#include <hip/hip_runtime.h>

// x [B=8, C=2, D=16, T=128000] fp32, x_wave [B=8, D=16, T=128000] fp32,
// pad_left = pad_right = 8, WINDOW=8, L=16, k=2.
//
//   out[b,c, seg*8+i - 8] = x[b,c,i,seg]  *w[b,i,seg]
//                         + x[b,c,i+8,seg-1]*w[b,i+8,seg-1],  i in [0,8), seg in [1,T)
//
// R2 post-mortem: scalar-dword streams (256 B/instr, 48 streams/wave, 512 KB
// apart) pinned HBM at ~2 TB/s (DRAM burst inefficiency). This version stages
// per-block tiles via float4 loads where a wave covers 4 KB contiguous per
// instruction, round-trips through LDS to absorb the seg-1 column shift, then
// computes from LDS (consecutive-lane reads, conflict-free).

constexpr int B = 8;
constexpr int C = 2;
constexpr int D = 16;
constexpr int T = 128000;

constexpr int TILE    = 256;   // segs per block
constexpr int NROW    = 48;    // 16 w rows + 32 x rows (c0,c1)
constexpr int NC4     = 66;    // float4 chunks/row: 264 floats = [tbase-8, tbase+256)
constexpr int LSTRIDE = 268;   // LDS row stride (floats): 16B-multiple, 268%32=12

__global__ __launch_bounds__(256) void oaa_tile_kernel(
    const float* __restrict__ x,
    const float* __restrict__ xw,
    float* __restrict__ out,
    int S)
{
    __shared__ float lds[NROW * LSTRIDE];

    const int b     = blockIdx.y;
    const int tbase = blockIdx.x * TILE;

    const float* wb = xw + (size_t)b * (D * T);      // 16 rows of T
    const float* xb = x  + (size_t)b * (C * D * T);  // 32 rows of T (c0 then c1)

    // ---- stage: 48 rows x 66 float4, lanes cover consecutive float4 ----
    for (int idx = threadIdx.x; idx < NROW * NC4; idx += 256) {
        const int row  = idx / NC4;
        const int col4 = idx - row * NC4;
        const int gc   = tbase - 8 + col4 * 4;       // global t of chunk start
        const float* src = (row < 16) ? (wb + row * T) : (xb + (row - 16) * T);
        float4 v = make_float4(0.f, 0.f, 0.f, 0.f);
        if (gc >= 0) v = *(const float4*)(src + gc); // high side always in-bounds
        *(float4*)(&lds[row * LSTRIDE + col4 * 4]) = v;
    }
    __syncthreads();

    // ---- compute: thread j handles seg = tbase + j ----
    const int j   = threadIdx.x;
    const int seg = tbase + j;
    if (seg >= 1 && seg < T) {
        const int c0 = j + 8;   // LDS col for t = seg      (= tbase-8 + c0)
        const int c1 = j + 7;   // LDS col for t = seg - 1

        float acc0[8], acc1[8];
#pragma unroll
        for (int i = 0; i < 8; ++i) {
            const float w0 = lds[i * LSTRIDE + c0];
            const float w1 = lds[(i + 8) * LSTRIDE + c1];
            const float a0 = lds[(16 + i) * LSTRIDE + c0];
            const float a1 = lds[(24 + i) * LSTRIDE + c1];
            const float b0 = lds[(32 + i) * LSTRIDE + c0];
            const float b1 = lds[(40 + i) * LSTRIDE + c1];
            acc0[i] = a0 * w0 + a1 * w1;   // c = 0
            acc1[i] = b0 * w0 + b1 * w1;   // c = 1
        }

        const size_t ob = (size_t)b * C * S;
        const int s0 = seg * 8 - 8;        // pad_left = 8
        float4* o0 = (float4*)(out + ob + s0);
        float4* o1 = (float4*)(out + ob + S + s0);
        o0[0] = make_float4(acc0[0], acc0[1], acc0[2], acc0[3]);
        o0[1] = make_float4(acc0[4], acc0[5], acc0[6], acc0[7]);
        o1[0] = make_float4(acc1[0], acc1[1], acc1[2], acc1[3]);
        o1[1] = make_float4(acc1[4], acc1[5], acc1[6], acc1[7]);
    }
}

extern "C" void kernel_launch(void* const* d_in, const int* in_sizes, int n_in,
                              void* d_out, int out_size, void* d_ws, size_t ws_size,
                              hipStream_t stream) {
    const float* x  = (const float*)d_in[0];
    const float* xw = (const float*)d_in[1];
    float* out = (float*)d_out;

    const int S = out_size / (B * C);        // 1023992
    const int ntile = T / TILE;              // 500 (covers segs 0..127999; seg 0 masked)
    dim3 grid(ntile, B);
    oaa_tile_kernel<<<grid, dim3(256), 0, stream>>>(x, xw, out, S);
}

// Round 5
// 257.692 us; speedup vs baseline: 1.0060x; 1.0060x over previous
//
#include <hip/hip_runtime.h>

// x [B=8, C=2, D=16, T=128000] fp32, x_wave [B=8, D=16, T=128000] fp32,
// pad_left = pad_right = 8, WINDOW=8, L=16, k=2.
//
//   out[b,c, seg*8+i - 8] = x[b,c,i,seg]  *w[b,i,seg]
//                         + x[b,c,i+8,seg-1]*w[b,i+8,seg-1],  i in [0,8), seg in [1,T)
//
// R3 post-mortem: staging loop had a load->ds_write dep per iteration and a
// non-unrollable trip count -> ~2 loads in flight per wave; stage/compute
// phases barrier-separated with 3 blocks/CU -> memory pipe ~50% duty. This
// version register-batches the staging: 13 fully-unrolled independent float4
// loads issued before ANY ds_write (13 wave-loads in flight, ~13 KB/wave),
// then LDS writes, one barrier, compute. Stores are non-temporal (output is
// write-once; don't evict x from L2/L3). R4 fixed: nontemporal builtin needs
// a native clang vector type, not HIP_vector_type<float,4>.

typedef float floatx4 __attribute__((ext_vector_type(4)));

constexpr int B = 8;
constexpr int C = 2;
constexpr int D = 16;
constexpr int T = 128000;

constexpr int TILE    = 256;   // segs per block
constexpr int NROW    = 48;    // 16 w rows + 32 x rows (c0,c1)
constexpr int NC4     = 66;    // float4 chunks/row: 264 floats = [tbase-8, tbase+256)
constexpr int NCHUNK  = NROW * NC4;        // 3168 float4 chunks per tile
constexpr int NITER   = (NCHUNK + 255) / 256;  // 13 chunks per thread (last partial)
constexpr int LSTRIDE = 268;   // LDS row stride (floats): 16B-multiple, 268%32=12

__global__ __launch_bounds__(256) void oaa_mlp_kernel(
    const float* __restrict__ x,
    const float* __restrict__ xw,
    float* __restrict__ out,
    int S)
{
    __shared__ float lds[NROW * LSTRIDE];

    const int b     = blockIdx.y;
    const int tbase = blockIdx.x * TILE;

    const float* wb = xw + (size_t)b * (D * T);      // 16 rows of T
    const float* xb = x  + (size_t)b * (C * D * T);  // 32 rows of T (c0 then c1)

    // ---- stage phase 1: issue ALL independent global loads into registers ----
    floatx4 v[NITER];
    int     laddr[NITER];
#pragma unroll
    for (int k = 0; k < NITER; ++k) {
        const int idx  = threadIdx.x + k * 256;
        const bool ok  = idx < NCHUNK;
        const int  id2 = ok ? idx : 0;
        const int row  = id2 / NC4;
        const int col4 = id2 - row * NC4;
        const int gc   = tbase - 8 + col4 * 4;       // global t of chunk start
        laddr[k] = ok ? (row * LSTRIDE + col4 * 4) : -1;
        const float* src = (row < 16) ? (wb + row * T)
                                      : (xb + (size_t)(row - 16) * T);
        v[k] = (floatx4)0.f;
        if (ok && gc >= 0)                           // high side always in-bounds
            v[k] = *(const floatx4*)(src + gc);
    }
    // ---- stage phase 2: drain into LDS ----
#pragma unroll
    for (int k = 0; k < NITER; ++k) {
        if (laddr[k] >= 0)
            *(floatx4*)(&lds[laddr[k]]) = v[k];
    }
    __syncthreads();

    // ---- compute: thread j handles seg = tbase + j ----
    const int j   = threadIdx.x;
    const int seg = tbase + j;
    if (seg >= 1 && seg < T) {
        const int c0 = j + 8;   // LDS col for t = seg
        const int c1 = j + 7;   // LDS col for t = seg - 1

        float acc0[8], acc1[8];
#pragma unroll
        for (int i = 0; i < 8; ++i) {
            const float w0 = lds[i * LSTRIDE + c0];
            const float w1 = lds[(i + 8) * LSTRIDE + c1];
            const float a0 = lds[(16 + i) * LSTRIDE + c0];
            const float a1 = lds[(24 + i) * LSTRIDE + c1];
            const float b0 = lds[(32 + i) * LSTRIDE + c0];
            const float b1 = lds[(40 + i) * LSTRIDE + c1];
            acc0[i] = a0 * w0 + a1 * w1;   // c = 0
            acc1[i] = b0 * w0 + b1 * w1;   // c = 1
        }

        const size_t ob = (size_t)b * C * S;
        const int s0 = seg * 8 - 8;        // pad_left = 8
        floatx4* o0 = (floatx4*)(out + ob + s0);
        floatx4* o1 = (floatx4*)(out + ob + S + s0);
        floatx4 r0 = {acc0[0], acc0[1], acc0[2], acc0[3]};
        floatx4 r1 = {acc0[4], acc0[5], acc0[6], acc0[7]};
        floatx4 r2 = {acc1[0], acc1[1], acc1[2], acc1[3]};
        floatx4 r3 = {acc1[4], acc1[5], acc1[6], acc1[7]};
        __builtin_nontemporal_store(r0, o0);
        __builtin_nontemporal_store(r1, o0 + 1);
        __builtin_nontemporal_store(r2, o1);
        __builtin_nontemporal_store(r3, o1 + 1);
    }
}

extern "C" void kernel_launch(void* const* d_in, const int* in_sizes, int n_in,
                              void* d_out, int out_size, void* d_ws, size_t ws_size,
                              hipStream_t stream) {
    const float* x  = (const float*)d_in[0];
    const float* xw = (const float*)d_in[1];
    float* out = (float*)d_out;

    const int S = out_size / (B * C);        // 1023992
    const int ntile = T / TILE;              // 500 (seg 0 masked in-kernel)
    dim3 grid(ntile, B);
    oaa_mlp_kernel<<<grid, dim3(256), 0, stream>>>(x, xw, out, S);
}